// Round 2
// baseline (351.956 us; speedup 1.0000x reference)
//
#include <hip/hip_runtime.h>
#include <stdint.h>

// Gator: logic-gate network forward, bit-packed over batch. Two kernels:
//   K1 (256 blocks): pack x into bit-planes, run 8 gate rows in LDS, dump the
//       9216 packed uint32 per 32-batch group to d_ws (9.4 MB).
//   K2 (2304 blocks): high-occupancy unpack of ws -> 302 MB float32 output.
// Round-1 lesson: fused version ran unpack at 1 block/CU (4 waves) -> 0.9 TB/s.
// Splitting lets the write-dominant phase run at full occupancy.

constexpr int B    = 8192;
constexpr int W0   = 1024;
constexpr int R    = 8;
constexpr int G    = 1024;
constexpr int WTOT = W0 + R * G;   // 9216
constexpr int BPB  = 32;           // batch elements (bits) per block
constexpr int NBG  = B / BPB;      // 256 batch groups
constexpr int NSLAB = WTOT / 1024; // 9 column slabs for unpack

__launch_bounds__(256, 1)
__global__ void gator_gates(const float* __restrict__ x,
                            const float* __restrict__ gates,
                            const int*   __restrict__ choices,
                            uint32_t*    __restrict__ ws) {
    __shared__ uint32_t cols[WTOT];      // bit b of cols[w] = (batch b0+b, col w)

    const int tid  = threadIdx.x;
    const int lane = tid & 63;
    const int wv   = tid >> 6;           // wave id 0..3
    const int bg   = blockIdx.x;
    const int half = lane >> 5;          // 0: lanes 0-31, 1: lanes 32-63
    const int row  = bg * BPB + (lane & 31);

    // ---- Phase A: pack input x[32 rows][1024 cols] into bit columns ----
    {
        const float4* xrow = (const float4*)(x + (size_t)row * W0);
        for (int it = 0; it < 32; ++it) {
            int c = wv * 256 + it * 8 + half * 4;
            float4 v = xrow[c >> 2];
            unsigned long long m0 = __ballot(v.x != 0.0f);
            unsigned long long m1 = __ballot(v.y != 0.0f);
            unsigned long long m2 = __ballot(v.z != 0.0f);
            unsigned long long m3 = __ballot(v.w != 0.0f);
            if ((lane & 31) == 0) {      // lane 0 -> cols c..c+3, lane 32 -> c+4..c+7
                int s = half * 32;
                cols[c + 0] = (uint32_t)(m0 >> s);
                cols[c + 1] = (uint32_t)(m1 >> s);
                cols[c + 2] = (uint32_t)(m2 >> s);
                cols[c + 3] = (uint32_t)(m3 >> s);
            }
        }
    }
    __syncthreads();

    // ---- Phase B: 8 gate rows, bitwise 4-entry LUT over 32 batch lanes ----
    {
        const int2*   ch2 = (const int2*)choices;   // [R*G] index pairs
        const float4* g4  = (const float4*)gates;   // [R*G] truth tables
        for (int r = 0; r < R; ++r) {
            for (int g = tid; g < G; g += 256) {
                int2     ch = ch2[r * G + g];
                uint32_t a  = cols[ch.x];
                uint32_t b  = cols[ch.y];
                float4   lt = g4[r * G + g];
                uint32_t o = 0u;
                o |= (lt.x != 0.0f) ? (~a & ~b) : 0u;   // a=0,b=0
                o |= (lt.y != 0.0f) ? (~a &  b) : 0u;   // a=0,b=1
                o |= (lt.z != 0.0f) ? ( a & ~b) : 0u;   // a=1,b=0
                o |= (lt.w != 0.0f) ? ( a &  b) : 0u;   // a=1,b=1
                cols[W0 + r * G + g] = o;
            }
            __syncthreads();
        }
    }

    // ---- Dump packed planes to workspace: ws[bg][0..9215] ----
    uint32_t* wrow = ws + (size_t)bg * WTOT;
    for (int w = tid * 4; w < WTOT; w += 1024) {
        *(uint4*)(wrow + w) = *(const uint4*)&cols[w];
    }
}

// Unpack: block (bg, slab) reads 1024 packed words, writes 32 rows x 1024 cols.
// No LDS, tiny VGPR -> high occupancy; pure write streaming.
__launch_bounds__(256)
__global__ void gator_unpack(const uint32_t* __restrict__ ws,
                             float* __restrict__ out) {
    const int tid  = threadIdx.x;
    const int bg   = blockIdx.x / NSLAB;
    const int slab = blockIdx.x % NSLAB;
    const int w    = slab * 1024 + tid * 4;

    uint4 c = *(const uint4*)(ws + (size_t)bg * WTOT + w);   // coalesced 16B/lane
    float* orow = out + (size_t)bg * BPB * WTOT + w;
    #pragma unroll
    for (int b = 0; b < BPB; ++b) {
        float4 v;
        v.x = (float)((c.x >> b) & 1u);
        v.y = (float)((c.y >> b) & 1u);
        v.z = (float)((c.z >> b) & 1u);
        v.w = (float)((c.w >> b) & 1u);
        *(float4*)(orow + (size_t)b * WTOT) = v;             // 1KB/wave contiguous
    }
}

extern "C" void kernel_launch(void* const* d_in, const int* in_sizes, int n_in,
                              void* d_out, int out_size, void* d_ws, size_t ws_size,
                              hipStream_t stream) {
    const float* x       = (const float*)d_in[0];
    const float* gates   = (const float*)d_in[1];
    const int*   choices = (const int*)d_in[2];
    float*       out     = (float*)d_out;
    uint32_t*    ws      = (uint32_t*)d_ws;

    gator_gates<<<dim3(NBG), dim3(256), 0, stream>>>(x, gates, choices, ws);
    gator_unpack<<<dim3(NBG * NSLAB), dim3(256), 0, stream>>>(ws, out);
}

// Round 3
// 337.356 us; speedup vs baseline: 1.0433x; 1.0433x over previous
//
#include <hip/hip_runtime.h>
#include <stdint.h>

// Gator: logic-gate network forward, bit-packed over batch. Single fused
// kernel, 256 blocks x 1024 threads (16 waves/CU).
//
// Round-2 lesson: neither round's compute kernels made the profile top-5
// (all slots are 194-202us harness poison fills) => kernels were already
// ~70-75us; dur_us carries ~275us of harness re-poison overhead. Stores are
// fire-and-forget so the unpack never needed occupancy. This round: drop the
// d_ws round-trip (19MB saved), widen blocks to 1024 threads to latency-hide
// pack/gates, and sit on the HBM floor: 302MB write + 33.5MB read ~= 53us.

constexpr int B    = 8192;
constexpr int W0   = 1024;
constexpr int R    = 8;
constexpr int G    = 1024;
constexpr int WTOT = W0 + R * G;   // 9216
constexpr int BPB  = 32;           // batch bits per block

__launch_bounds__(1024, 1)
__global__ void gator_fused(const float* __restrict__ x,
                            const float* __restrict__ gates,
                            const int*   __restrict__ choices,
                            float*       __restrict__ out) {
    __shared__ uint32_t cols[WTOT];      // bit b of cols[w] = (batch b0+b, col w)

    const int tid  = threadIdx.x;
    const int lane = tid & 63;
    const int wv   = tid >> 6;           // wave id 0..15
    const int bg   = blockIdx.x;
    const int half = lane >> 5;          // 0: lanes 0-31, 1: lanes 32-63
    const int row  = bg * BPB + (lane & 31);

    // ---- Phase A: pack x[32 rows][1024 cols] into bit columns ----
    // Wave wv covers cols [wv*64, wv*64+64); 8 cols per iteration via ballot.
    {
        const float4* xrow = (const float4*)(x + (size_t)row * W0);
        #pragma unroll
        for (int it = 0; it < 8; ++it) {
            int c = wv * 64 + it * 8 + half * 4;
            float4 v = xrow[c >> 2];
            unsigned long long m0 = __ballot(v.x != 0.0f);
            unsigned long long m1 = __ballot(v.y != 0.0f);
            unsigned long long m2 = __ballot(v.z != 0.0f);
            unsigned long long m3 = __ballot(v.w != 0.0f);
            if ((lane & 31) == 0) {      // lane 0 -> cols c..c+3, lane 32 -> c+4..c+7
                int s = half * 32;
                cols[c + 0] = (uint32_t)(m0 >> s);
                cols[c + 1] = (uint32_t)(m1 >> s);
                cols[c + 2] = (uint32_t)(m2 >> s);
                cols[c + 3] = (uint32_t)(m3 >> s);
            }
        }
    }
    __syncthreads();

    // ---- Phase B: 8 gate rows, one gate per thread per row ----
    {
        const int2*   ch2 = (const int2*)choices;   // [R*G] index pairs
        const float4* g4  = (const float4*)gates;   // [R*G] truth tables
        for (int r = 0; r < R; ++r) {
            int2     ch = ch2[r * G + tid];
            uint32_t a  = cols[ch.x];
            uint32_t b  = cols[ch.y];
            float4   lt = g4[r * G + tid];
            uint32_t o = 0u;
            o |= (lt.x != 0.0f) ? (~a & ~b) : 0u;   // a=0,b=0
            o |= (lt.y != 0.0f) ? (~a &  b) : 0u;   // a=0,b=1
            o |= (lt.z != 0.0f) ? ( a & ~b) : 0u;   // a=1,b=0
            o |= (lt.w != 0.0f) ? ( a &  b) : 0u;   // a=1,b=1
            cols[W0 + r * G + tid] = o;
            __syncthreads();
        }
    }

    // ---- Phase C: unpack all 9216 columns to float32 ----
    // Thread t owns cols {t*4, t*4+4096, t*4+8192}; 32 batch bits each,
    // coalesced float4 stores (1KB/wave contiguous), fire-and-forget.
    for (int w = tid * 4; w < WTOT; w += 4096) {
        uint4 c = *(const uint4*)&cols[w];
        float* orow = out + (size_t)bg * BPB * WTOT + w;
        #pragma unroll
        for (int b = 0; b < BPB; ++b) {
            float4 v;
            v.x = (float)((c.x >> b) & 1u);
            v.y = (float)((c.y >> b) & 1u);
            v.z = (float)((c.z >> b) & 1u);
            v.w = (float)((c.w >> b) & 1u);
            *(float4*)(orow + (size_t)b * WTOT) = v;
        }
    }
}

extern "C" void kernel_launch(void* const* d_in, const int* in_sizes, int n_in,
                              void* d_out, int out_size, void* d_ws, size_t ws_size,
                              hipStream_t stream) {
    const float* x       = (const float*)d_in[0];
    const float* gates   = (const float*)d_in[1];
    const int*   choices = (const int*)d_in[2];
    float*       out     = (float*)d_out;
    (void)d_ws; (void)ws_size;

    gator_fused<<<dim3(B / BPB), dim3(1024), 0, stream>>>(x, gates, choices, out);
}